// Round 18
// baseline (39.528 us; speedup 1.0000x reference)
//
#include <hip/hip_runtime.h>

// Problem constants (fixed by the reference): B=32, N=128, L=16, F=32, NAVG=50
#define BB 32
#define NN 128
#define LL 16
#define FF 32
#define PADL 20              // padded LDS row stride (floats): 80B, conflict-free reads
constexpr float INV_NAVG = 1.0f / 50.0f;

// ---------------------------------------------------------------------------
// Kernel A: per 4 rows (b,i):
//   rw3[b,i,f]  = sum_l rs_i[l] * w[l,3,f]      (rs = scaled rowsum)
//   a2p[b,i,f]  = sum_l rs_i[l] * w[l,2,f]
//   rwDp[b,i,f] = sum_l rs_i[l] * w[l,4,f]
//   tsp[blk,l]  = partial (over 4 rows) of scaled rowsum   (for k_tot)
// 1024 blocks x 256 threads. Coalesced float4 loads, LDS tree reduce.
// ---------------------------------------------------------------------------
__global__ __launch_bounds__(256) void k_rowsum(const float* __restrict__ in,
                                                const float* __restrict__ w,
                                                float* __restrict__ tsp,
                                                float* __restrict__ rw3,
                                                float* __restrict__ a2p,
                                                float* __restrict__ rwDp) {
    __shared__ float4 red4[4][256];      // 16KB
    const int t = threadIdx.x;
    const int blk = blockIdx.x;
    const int rowBase = blk * 4;         // global row = b*128 + i
    const int b = rowBase >> 7, i0 = rowBase & 127;

    const float4* in4 = reinterpret_cast<const float4*>(in);
#pragma unroll
    for (int r = 0; r < 4; ++r) {
        size_t base = (size_t)(rowBase + r) * (NN * LL / 4);   // 512 float4/row
        float4 u = in4[base + t];
        float4 v = in4[base + t + 256];
        float4 a;
        a.x = u.x + v.x; a.y = u.y + v.y; a.z = u.z + v.z; a.w = u.w + v.w;
        red4[r][t] = a;
    }
    __syncthreads();
#pragma unroll
    for (int s = 32; s >= 1; s >>= 1) {          // reduce j-groups: 64 -> 1
        if (t < s * 4) {
#pragma unroll
            for (int r = 0; r < 4; ++r) {
                float4 a = red4[r][t], c = red4[r][t + s * 4];
                a.x += c.x; a.y += c.y; a.z += c.z; a.w += c.w;
                red4[r][t] = a;
            }
        }
        __syncthreads();
    }
    // red4[r][0..3] now hold RAW row sums (16 floats per row), LDS-broadcastable.

    if (t < 16) {    // partial totsum for l=t over the block's 4 rows (scaled once)
        int cc = t >> 2, comp = t & 3;
        float s = 0.f;
#pragma unroll
        for (int r2 = 0; r2 < 4; ++r2)
            s += reinterpret_cast<const float*>(&red4[r2][cc])[comp];
        tsp[(size_t)blk * LL + t] = s * INV_NAVG;   // b = blk>>5, slot = blk&31
    }

    if (t < 128) {   // rw3 for the block's 4 rows
        int r = t >> 5, f = t & 31;
        const float* rowRaw = reinterpret_cast<const float*>(&red4[r][0]);
        float v = 0.f;
#pragma unroll
        for (int q = 0; q < LL; ++q)
            v += rowRaw[q] * w[(q * 6 + 3) * FF + f];
        rw3[((size_t)b * NN + i0 + r) * FF + f] = v * INV_NAVG;
    } else {         // a2p, rwDp for the block's 4 rows
        int r = (t - 128) >> 5, f = t & 31;
        const float* rowRaw = reinterpret_cast<const float*>(&red4[r][0]);
        float s2 = 0.f, s4 = 0.f;
#pragma unroll
        for (int q = 0; q < LL; ++q) {
            float rv = rowRaw[q];
            s2 += rv * w[(q * 6 + 2) * FF + f];
            s4 += rv * w[(q * 6 + 4) * FF + f];
        }
        size_t o = ((size_t)b * NN + i0 + r) * FF + f;
        a2p[o]  = s2 * INV_NAVG;
        rwDp[o] = s4 * INV_NAVG;
    }
}

// ---------------------------------------------------------------------------
// Kernel T: 32 blocks (one per b). tsp[32 slots][16] -> tot[l], then
//   tb[b,f]  = sum_l tot*w[l,1,f] + bias[f]
//   ttd[b,f] = sum_l tot*w[l,5,f] + diag_bias[f]
// ---------------------------------------------------------------------------
__global__ __launch_bounds__(256) void k_tot(const float* __restrict__ tsp,
                                             const float* __restrict__ w,
                                             const float* __restrict__ bias,
                                             const float* __restrict__ dbias,
                                             float* __restrict__ tb,
                                             float* __restrict__ ttd) {
    __shared__ float red[256];
    __shared__ float tot[LL];
    const int t = threadIdx.x;
    const int b = blockIdx.x;

    red[t] = tsp[(size_t)b * 512 + t] + tsp[(size_t)b * 512 + 256 + t];
    __syncthreads();
#pragma unroll
    for (int st = 8; st >= 1; st >>= 1) {
        if (t < st * 16) red[t] += red[t + st * 16];
        __syncthreads();
    }
    if (t < LL) tot[t] = red[t] * INV_NAVG;
    __syncthreads();

    if (t < 64) {
        int f = t & 31, sel = t >> 5;
        const float* base = sel ? dbias : bias;
        int op = sel ? 5 : 1;
        float v = base[f];
#pragma unroll
        for (int q = 0; q < LL; ++q)
            v += tot[q] * w[(q * 6 + op) * FF + f];
        (sel ? ttd : tb)[b * FF + f] = v;
    }
}

// ---------------------------------------------------------------------------
// Kernel M (R16 structure + f2-split for occupancy):
// 4096 blocks x 256 threads, one row each, XCD-affinity swizzle, ONE barrier,
// all loads hoisted. f2=t&15 owns f=2f2..2f2+1 -> w0r is 32 VGPR, total ~40
// (R15 measured) -> 8 blocks/CU (2x the f4-split champion). Stores are PLAIN
// float2 (R15 lesson: 8B nontemporal stores bypass L2 write-combining and
// double HBM write traffic; cached 8B stores coalesce to 512B/wave-inst).
// jsub=t>>4 owns j=jsub+16p (p<8).
// ---------------------------------------------------------------------------
__global__ __launch_bounds__(256) void k_main(const float* __restrict__ in,
                                              const float* __restrict__ w,
                                              const float* __restrict__ rw3,
                                              const float* __restrict__ a2p,
                                              const float* __restrict__ rwDp,
                                              const float* __restrict__ tb,
                                              const float* __restrict__ ttd,
                                              float* __restrict__ out) {
    __shared__ float inRow[NN * PADL];   // 10.25KB padded
    const int t = threadIdx.x;
    const int blk = blockIdx.x;
    // XCD-affinity permutation: row = 32m + 4*(blk&7) + ((blk>>3)&3)
    const int row = ((blk >> 5) << 5) + ((blk & 7) << 2) + ((blk >> 3) & 3);
    const int b = row >> 7, i = row & 127;

    // stage input row (coalesced float4 loads, padded LDS writes)
    const float4* src4 = reinterpret_cast<const float4*>(in + (size_t)row * (NN * LL));
#pragma unroll
    for (int m = 0; m < 2; ++m) {
        int idx = t + 256 * m;           // 0..511
        int j = idx >> 2, c = idx & 3;
        *reinterpret_cast<float4*>(&inRow[j * PADL + c * 4]) = src4[idx];
    }

    const int f2 = t & 15;               // f = 2*f2, 2*f2+1
    const int jsub = t >> 4;             // 0..15
    float2 w0r[LL];                      // 32 VGPR
#pragma unroll
    for (int q = 0; q < LL; ++q)
        w0r[q] = *reinterpret_cast<const float2*>(&w[q * 6 * FF + 2 * f2]);

    float2 av = *reinterpret_cast<const float2*>(&a2p[(size_t)row * FF + 2 * f2]);
    float2 tv = *reinterpret_cast<const float2*>(&tb[b * FF + 2 * f2]);
    av.x += tv.x; av.y += tv.y;
    float2 dv = *reinterpret_cast<const float2*>(&rwDp[(size_t)row * FF + 2 * f2]);
    float2 td = *reinterpret_cast<const float2*>(&ttd[b * FF + 2 * f2]);
    dv.x += td.x; dv.y += td.y;

    const float* rw3b = rw3 + (size_t)b * NN * FF + 2 * f2;
    float* outb = out + (size_t)row * NN * FF + 2 * f2;

    // hoist all 8 rw3 loads (L2, 512B-contiguous per wave inst)
    float2 rv[8];
#pragma unroll
    for (int p = 0; p < 8; ++p)
        rv[p] = *reinterpret_cast<const float2*>(&rw3b[(size_t)(jsub + 16 * p) * FF]);

    __syncthreads();

#pragma unroll 4
    for (int p = 0; p < 8; ++p) {
        int j = jsub + 16 * p;
        float ax = av.x + rv[p].x;
        float ay = av.y + rv[p].y;
        if (j == i) { ax += dv.x; ay += dv.y; }
        const float4* xr = reinterpret_cast<const float4*>(&inRow[j * PADL]);
        float4 x0 = xr[0], x1 = xr[1], x2 = xr[2], x3 = xr[3];
        ax += x0.x * w0r[0].x + x0.y * w0r[1].x + x0.z * w0r[2].x + x0.w * w0r[3].x
            + x1.x * w0r[4].x + x1.y * w0r[5].x + x1.z * w0r[6].x + x1.w * w0r[7].x
            + x2.x * w0r[8].x + x2.y * w0r[9].x + x2.z * w0r[10].x + x2.w * w0r[11].x
            + x3.x * w0r[12].x + x3.y * w0r[13].x + x3.z * w0r[14].x + x3.w * w0r[15].x;
        ay += x0.x * w0r[0].y + x0.y * w0r[1].y + x0.z * w0r[2].y + x0.w * w0r[3].y
            + x1.x * w0r[4].y + x1.y * w0r[5].y + x1.z * w0r[6].y + x1.w * w0r[7].y
            + x2.x * w0r[8].y + x2.y * w0r[9].y + x2.z * w0r[10].y + x2.w * w0r[11].y
            + x3.x * w0r[12].y + x3.y * w0r[13].y + x3.z * w0r[14].y + x3.w * w0r[15].y;
        float2 o;
        o.x = fmaxf(ax, 0.f);
        o.y = fmaxf(ay, 0.f);
        *reinterpret_cast<float2*>(&outb[(size_t)j * FF]) = o;
    }
}

extern "C" void kernel_launch(void* const* d_in, const int* in_sizes, int n_in,
                              void* d_out, int out_size, void* d_ws, size_t ws_size,
                              hipStream_t stream) {
    const float* in    = (const float*)d_in[0];   // [B,N,N,L] fp32
    const float* w     = (const float*)d_in[1];   // [L,6,F]
    const float* bias  = (const float*)d_in[2];   // [F]
    const float* dbias = (const float*)d_in[3];   // [F]
    float* out = (float*)d_out;                   // [B,N,N,F] fp32
    float* ws  = (float*)d_ws;

    float* tsp  = ws;                                  // 1024*16  = 16384 floats
    float* rw3  = tsp  + (size_t)1024 * LL;            // B*N*F    = 131072
    float* a2p  = rw3  + (size_t)BB * NN * FF;         // 131072
    float* rwDp = a2p  + (size_t)BB * NN * FF;         // 131072
    float* tb   = rwDp + (size_t)BB * NN * FF;         // B*F      = 1024
    float* ttd  = tb   + (size_t)BB * FF;              // 1024   (~1.65MB total)

    k_rowsum<<<BB * NN / 4, 256, 0, stream>>>(in, w, tsp, rw3, a2p, rwDp);
    k_tot   <<<BB,          256, 0, stream>>>(tsp, w, bias, dbias, tb, ttd);
    k_main  <<<BB * NN,     256, 0, stream>>>(in, w, rw3, a2p, rwDp, tb, ttd, out);
}

// Round 19
// 30.511 us; speedup vs baseline: 1.2955x; 1.2955x over previous
//
#include <hip/hip_runtime.h>

// Problem constants (fixed by the reference): B=32, N=128, L=16, F=32, NAVG=50
#define BB 32
#define NN 128
#define LL 16
#define FF 32
#define PADL 20              // padded LDS row stride (floats): 80B, conflict-free reads
constexpr float INV_NAVG = 1.0f / 50.0f;

typedef float nfloat4 __attribute__((ext_vector_type(4)));   // clang-native 16B vector

// ---------------------------------------------------------------------------
// Kernel A: per 4 rows (b,i):
//   rw3[b,i,f]  = sum_l rs_i[l] * w[l,3,f]      (rs = scaled rowsum)
//   a2p[b,i,f]  = sum_l rs_i[l] * w[l,2,f]
//   rwDp[b,i,f] = sum_l rs_i[l] * w[l,4,f]
//   tsp[blk,l]  = partial (over 4 rows) of scaled rowsum   (for k_tot)
// 1024 blocks x 256 threads. Coalesced float4 loads, LDS tree reduce.
// ---------------------------------------------------------------------------
__global__ __launch_bounds__(256) void k_rowsum(const float* __restrict__ in,
                                                const float* __restrict__ w,
                                                float* __restrict__ tsp,
                                                float* __restrict__ rw3,
                                                float* __restrict__ a2p,
                                                float* __restrict__ rwDp) {
    __shared__ float4 red4[4][256];      // 16KB
    const int t = threadIdx.x;
    const int blk = blockIdx.x;
    const int rowBase = blk * 4;         // global row = b*128 + i
    const int b = rowBase >> 7, i0 = rowBase & 127;

    const float4* in4 = reinterpret_cast<const float4*>(in);
#pragma unroll
    for (int r = 0; r < 4; ++r) {
        size_t base = (size_t)(rowBase + r) * (NN * LL / 4);   // 512 float4/row
        float4 u = in4[base + t];
        float4 v = in4[base + t + 256];
        float4 a;
        a.x = u.x + v.x; a.y = u.y + v.y; a.z = u.z + v.z; a.w = u.w + v.w;
        red4[r][t] = a;
    }
    __syncthreads();
#pragma unroll
    for (int s = 32; s >= 1; s >>= 1) {          // reduce j-groups: 64 -> 1
        if (t < s * 4) {
#pragma unroll
            for (int r = 0; r < 4; ++r) {
                float4 a = red4[r][t], c = red4[r][t + s * 4];
                a.x += c.x; a.y += c.y; a.z += c.z; a.w += c.w;
                red4[r][t] = a;
            }
        }
        __syncthreads();
    }
    // red4[r][0..3] now hold RAW row sums (16 floats per row), LDS-broadcastable.

    if (t < 16) {    // partial totsum for l=t over the block's 4 rows (scaled once)
        int cc = t >> 2, comp = t & 3;
        float s = 0.f;
#pragma unroll
        for (int r2 = 0; r2 < 4; ++r2)
            s += reinterpret_cast<const float*>(&red4[r2][cc])[comp];
        tsp[(size_t)blk * LL + t] = s * INV_NAVG;   // b = blk>>5, slot = blk&31
    }

    if (t < 128) {   // rw3 for the block's 4 rows
        int r = t >> 5, f = t & 31;
        const float* rowRaw = reinterpret_cast<const float*>(&red4[r][0]);
        float v = 0.f;
#pragma unroll
        for (int q = 0; q < LL; ++q)
            v += rowRaw[q] * w[(q * 6 + 3) * FF + f];
        rw3[((size_t)b * NN + i0 + r) * FF + f] = v * INV_NAVG;
    } else {         // a2p, rwDp for the block's 4 rows
        int r = (t - 128) >> 5, f = t & 31;
        const float* rowRaw = reinterpret_cast<const float*>(&red4[r][0]);
        float s2 = 0.f, s4 = 0.f;
#pragma unroll
        for (int q = 0; q < LL; ++q) {
            float rv = rowRaw[q];
            s2 += rv * w[(q * 6 + 2) * FF + f];
            s4 += rv * w[(q * 6 + 4) * FF + f];
        }
        size_t o = ((size_t)b * NN + i0 + r) * FF + f;
        a2p[o]  = s2 * INV_NAVG;
        rwDp[o] = s4 * INV_NAVG;
    }
}

// ---------------------------------------------------------------------------
// Kernel T: 32 blocks (one per b). tsp[32 slots][16] -> tot[l], then
//   tb[b,f]  = sum_l tot*w[l,1,f] + bias[f]
//   ttd[b,f] = sum_l tot*w[l,5,f] + diag_bias[f]
// ---------------------------------------------------------------------------
__global__ __launch_bounds__(256) void k_tot(const float* __restrict__ tsp,
                                             const float* __restrict__ w,
                                             const float* __restrict__ bias,
                                             const float* __restrict__ dbias,
                                             float* __restrict__ tb,
                                             float* __restrict__ ttd) {
    __shared__ float red[256];
    __shared__ float tot[LL];
    const int t = threadIdx.x;
    const int b = blockIdx.x;

    red[t] = tsp[(size_t)b * 512 + t] + tsp[(size_t)b * 512 + 256 + t];
    __syncthreads();
#pragma unroll
    for (int st = 8; st >= 1; st >>= 1) {
        if (t < st * 16) red[t] += red[t + st * 16];
        __syncthreads();
    }
    if (t < LL) tot[t] = red[t] * INV_NAVG;
    __syncthreads();

    if (t < 64) {
        int f = t & 31, sel = t >> 5;
        const float* base = sel ? dbias : bias;
        int op = sel ? 5 : 1;
        float v = base[f];
#pragma unroll
        for (int q = 0; q < LL; ++q)
            v += tot[q] * w[(q * 6 + op) * FF + f];
        (sel ? ttd : tb)[b * FF + f] = v;
    }
}

// ---------------------------------------------------------------------------
// Kernel M (4-row software-pipelined): 1024 blocks x 256 threads, 4 rows
// (same b) per block, 1:1 with k_rowsum blocks (perfect XCD/L2 affinity).
// Double-buffered LDS. Per-block (once): w0r, tv/td, rv (rw3 is row-
// independent!). Per-row: stage + a2p/rwDp prefetched a full compute phase
// ahead; ONE barrier per row; champion f4 hot loop; nt float4 stores.
// ---------------------------------------------------------------------------
__global__ __launch_bounds__(256) void k_main(const float* __restrict__ in,
                                              const float* __restrict__ w,
                                              const float* __restrict__ rw3,
                                              const float* __restrict__ a2p,
                                              const float* __restrict__ rwDp,
                                              const float* __restrict__ tb,
                                              const float* __restrict__ ttd,
                                              float* __restrict__ out) {
    __shared__ float inRow[2][NN * PADL];   // 20.5KB (double buffer)
    const int t = threadIdx.x;
    const int blk = blockIdx.x;          // matches k_rowsum block exactly
    const int rowBase = blk * 4;
    const int b = rowBase >> 7, i0 = rowBase & 127;
    const int fq = t & 7;                // f base = 4*fq
    const int jg = t >> 3;               // 0..31

    // ---- per-block hoisted loads ----
    float4 w0r[LL];
#pragma unroll
    for (int q = 0; q < LL; ++q)
        w0r[q] = *reinterpret_cast<const float4*>(&w[q * 6 * FF + 4 * fq]);
    const float4 tv = *reinterpret_cast<const float4*>(&tb[b * FF + 4 * fq]);
    const float4 td = *reinterpret_cast<const float4*>(&ttd[b * FF + 4 * fq]);
    const float* rw3b = rw3 + (size_t)b * NN * FF + 4 * fq;
    float4 rv[4];                        // shared by all 4 rows (same b)
#pragma unroll
    for (int p = 0; p < 4; ++p)
        rv[p] = *reinterpret_cast<const float4*>(&rw3b[(size_t)(jg + 32 * p) * FF]);

    const float4* src4 = reinterpret_cast<const float4*>(in) + (size_t)rowBase * 512;

    // ---- row 0: stage + av/dv ----
    float4 sa = src4[t], sb = src4[t + 256];
    float4 avc = *reinterpret_cast<const float4*>(&a2p[(size_t)rowBase * FF + 4 * fq]);
    float4 dvc = *reinterpret_cast<const float4*>(&rwDp[(size_t)rowBase * FF + 4 * fq]);
    avc.x += tv.x; avc.y += tv.y; avc.z += tv.z; avc.w += tv.w;
    dvc.x += td.x; dvc.y += td.y; dvc.z += td.z; dvc.w += td.w;
    {
        int j = t >> 2, c = t & 3;
        *reinterpret_cast<float4*>(&inRow[0][j * PADL + c * 4]) = sa;
        int idx = t + 256;
        j = idx >> 2; c = idx & 3;
        *reinterpret_cast<float4*>(&inRow[0][j * PADL + c * 4]) = sb;
    }
    __syncthreads();

#pragma unroll
    for (int r = 0; r < 4; ++r) {
        // prefetch next row (loads issue before this row's compute)
        float4 sna, snb, avn, dvn;
        if (r < 3) {
            sna = src4[(r + 1) * 512 + t];
            snb = src4[(r + 1) * 512 + t + 256];
            avn = *reinterpret_cast<const float4*>(&a2p[(size_t)(rowBase + r + 1) * FF + 4 * fq]);
            dvn = *reinterpret_cast<const float4*>(&rwDp[(size_t)(rowBase + r + 1) * FF + 4 * fq]);
        }

        const float* buf = inRow[r & 1];
        float* outr = out + (size_t)(rowBase + r) * NN * FF + 4 * fq;
        const int i = i0 + r;

#pragma unroll
        for (int p = 0; p < 4; ++p) {
            int j = jg + 32 * p;
            float4 acc;
            acc.x = avc.x + rv[p].x;
            acc.y = avc.y + rv[p].y;
            acc.z = avc.z + rv[p].z;
            acc.w = avc.w + rv[p].w;
            if (j == i) {
                acc.x += dvc.x; acc.y += dvc.y; acc.z += dvc.z; acc.w += dvc.w;
            }
            const float4* xr = reinterpret_cast<const float4*>(&buf[j * PADL]);
            float xv[LL];
            *reinterpret_cast<float4*>(&xv[0])  = xr[0];
            *reinterpret_cast<float4*>(&xv[4])  = xr[1];
            *reinterpret_cast<float4*>(&xv[8])  = xr[2];
            *reinterpret_cast<float4*>(&xv[12]) = xr[3];
#pragma unroll
            for (int q = 0; q < LL; ++q) {
                acc.x += xv[q] * w0r[q].x;
                acc.y += xv[q] * w0r[q].y;
                acc.z += xv[q] * w0r[q].z;
                acc.w += xv[q] * w0r[q].w;
            }
            nfloat4 o;
            o.x = fmaxf(acc.x, 0.f);
            o.y = fmaxf(acc.y, 0.f);
            o.z = fmaxf(acc.z, 0.f);
            o.w = fmaxf(acc.w, 0.f);
            __builtin_nontemporal_store(o, reinterpret_cast<nfloat4*>(&outr[(size_t)j * FF]));
        }

        if (r < 3) {
            // write next buffer (loads have had the whole compute phase to land)
            float* nbuf = inRow[(r + 1) & 1];
            int j = t >> 2, c = t & 3;
            *reinterpret_cast<float4*>(&nbuf[j * PADL + c * 4]) = sna;
            int idx = t + 256;
            j = idx >> 2; c = idx & 3;
            *reinterpret_cast<float4*>(&nbuf[j * PADL + c * 4]) = snb;
            avc.x = avn.x + tv.x; avc.y = avn.y + tv.y;
            avc.z = avn.z + tv.z; avc.w = avn.w + tv.w;
            dvc.x = dvn.x + td.x; dvc.y = dvn.y + td.y;
            dvc.z = dvn.z + td.z; dvc.w = dvn.w + td.w;
        }
        __syncthreads();
    }
}

extern "C" void kernel_launch(void* const* d_in, const int* in_sizes, int n_in,
                              void* d_out, int out_size, void* d_ws, size_t ws_size,
                              hipStream_t stream) {
    const float* in    = (const float*)d_in[0];   // [B,N,N,L] fp32
    const float* w     = (const float*)d_in[1];   // [L,6,F]
    const float* bias  = (const float*)d_in[2];   // [F]
    const float* dbias = (const float*)d_in[3];   // [F]
    float* out = (float*)d_out;                   // [B,N,N,F] fp32
    float* ws  = (float*)d_ws;

    float* tsp  = ws;                                  // 1024*16  = 16384 floats
    float* rw3  = tsp  + (size_t)1024 * LL;            // B*N*F    = 131072
    float* a2p  = rw3  + (size_t)BB * NN * FF;         // 131072
    float* rwDp = a2p  + (size_t)BB * NN * FF;         // 131072
    float* tb   = rwDp + (size_t)BB * NN * FF;         // B*F      = 1024
    float* ttd  = tb   + (size_t)BB * FF;              // 1024   (~1.65MB total)

    k_rowsum<<<BB * NN / 4, 256, 0, stream>>>(in, w, tsp, rw3, a2p, rwDp);
    k_tot   <<<BB,          256, 0, stream>>>(tsp, w, bias, dbias, tb, ttd);
    k_main  <<<BB * NN / 4, 256, 0, stream>>>(in, w, rw3, a2p, rwDp, tb, ttd, out);
}

// Round 21
// 30.433 us; speedup vs baseline: 1.2988x; 1.0025x over previous
//
#include <hip/hip_runtime.h>

// Problem constants (fixed by the reference): B=32, N=128, L=16, F=32, NAVG=50
#define BB 32
#define NN 128
#define LL 16
#define FF 32
#define PADL 20              // padded LDS row stride (floats): 80B, conflict-free reads
constexpr float INV_NAVG = 1.0f / 50.0f;

typedef float nfloat4 __attribute__((ext_vector_type(4)));   // clang-native 16B vector

// ---------------------------------------------------------------------------
// Kernel A: per 4 rows (b,i):
//   rw3[b,i,f]  = sum_l rs_i[l] * w[l,3,f]      (rs = scaled rowsum)
//   a2p[b,i,f]  = sum_l rs_i[l] * w[l,2,f]
//   rwDp[b,i,f] = sum_l rs_i[l] * w[l,4,f]
//   tsp[blk,l]  = partial (over 4 rows) of scaled rowsum   (for k_tot)
// 1024 blocks x 256 threads. Coalesced float4 loads, LDS tree reduce.
// ---------------------------------------------------------------------------
__global__ __launch_bounds__(256) void k_rowsum(const float* __restrict__ in,
                                                const float* __restrict__ w,
                                                float* __restrict__ tsp,
                                                float* __restrict__ rw3,
                                                float* __restrict__ a2p,
                                                float* __restrict__ rwDp) {
    __shared__ float4 red4[4][256];      // 16KB
    const int t = threadIdx.x;
    const int blk = blockIdx.x;
    const int rowBase = blk * 4;         // global row = b*128 + i
    const int b = rowBase >> 7, i0 = rowBase & 127;

    const float4* in4 = reinterpret_cast<const float4*>(in);
#pragma unroll
    for (int r = 0; r < 4; ++r) {
        size_t base = (size_t)(rowBase + r) * (NN * LL / 4);   // 512 float4/row
        float4 u = in4[base + t];
        float4 v = in4[base + t + 256];
        float4 a;
        a.x = u.x + v.x; a.y = u.y + v.y; a.z = u.z + v.z; a.w = u.w + v.w;
        red4[r][t] = a;
    }
    __syncthreads();
#pragma unroll
    for (int s = 32; s >= 1; s >>= 1) {          // reduce j-groups: 64 -> 1
        if (t < s * 4) {
#pragma unroll
            for (int r = 0; r < 4; ++r) {
                float4 a = red4[r][t], c = red4[r][t + s * 4];
                a.x += c.x; a.y += c.y; a.z += c.z; a.w += c.w;
                red4[r][t] = a;
            }
        }
        __syncthreads();
    }
    // red4[r][0..3] now hold RAW row sums (16 floats per row), LDS-broadcastable.

    if (t < 16) {    // partial totsum for l=t over the block's 4 rows (scaled once)
        int cc = t >> 2, comp = t & 3;
        float s = 0.f;
#pragma unroll
        for (int r2 = 0; r2 < 4; ++r2)
            s += reinterpret_cast<const float*>(&red4[r2][cc])[comp];
        tsp[(size_t)blk * LL + t] = s * INV_NAVG;   // b = blk>>5, slot = blk&31
    }

    if (t < 128) {   // rw3 for the block's 4 rows
        int r = t >> 5, f = t & 31;
        const float* rowRaw = reinterpret_cast<const float*>(&red4[r][0]);
        float v = 0.f;
#pragma unroll
        for (int q = 0; q < LL; ++q)
            v += rowRaw[q] * w[(q * 6 + 3) * FF + f];
        rw3[((size_t)b * NN + i0 + r) * FF + f] = v * INV_NAVG;
    } else {         // a2p, rwDp for the block's 4 rows
        int r = (t - 128) >> 5, f = t & 31;
        const float* rowRaw = reinterpret_cast<const float*>(&red4[r][0]);
        float s2 = 0.f, s4 = 0.f;
#pragma unroll
        for (int q = 0; q < LL; ++q) {
            float rv = rowRaw[q];
            s2 += rv * w[(q * 6 + 2) * FF + f];
            s4 += rv * w[(q * 6 + 4) * FF + f];
        }
        size_t o = ((size_t)b * NN + i0 + r) * FF + f;
        a2p[o]  = s2 * INV_NAVG;
        rwDp[o] = s4 * INV_NAVG;
    }
}

// ---------------------------------------------------------------------------
// Kernel T: 32 blocks (one per b). tsp[32 slots][16] -> tot[l], then
//   tb[b,f]  = sum_l tot*w[l,1,f] + bias[f]
//   ttd[b,f] = sum_l tot*w[l,5,f] + diag_bias[f]
// ---------------------------------------------------------------------------
__global__ __launch_bounds__(256) void k_tot(const float* __restrict__ tsp,
                                             const float* __restrict__ w,
                                             const float* __restrict__ bias,
                                             const float* __restrict__ dbias,
                                             float* __restrict__ tb,
                                             float* __restrict__ ttd) {
    __shared__ float red[256];
    __shared__ float tot[LL];
    const int t = threadIdx.x;
    const int b = blockIdx.x;

    red[t] = tsp[(size_t)b * 512 + t] + tsp[(size_t)b * 512 + 256 + t];
    __syncthreads();
#pragma unroll
    for (int st = 8; st >= 1; st >>= 1) {
        if (t < st * 16) red[t] += red[t + st * 16];
        __syncthreads();
    }
    if (t < LL) tot[t] = red[t] * INV_NAVG;
    __syncthreads();

    if (t < 64) {
        int f = t & 31, sel = t >> 5;
        const float* base = sel ? dbias : bias;
        int op = sel ? 5 : 1;
        float v = base[f];
#pragma unroll
        for (int q = 0; q < LL; ++q)
            v += tot[q] * w[(q * 6 + op) * FF + f];
        (sel ? ttd : tb)[b * FF + f] = v;
    }
}

// ---------------------------------------------------------------------------
// Kernel M (4-row software-pipelined): 1024 blocks x 256 threads, 4 rows
// (same b) per block, 1:1 with k_rowsum blocks (perfect XCD/L2 affinity).
// Double-buffered LDS. Per-block (once): w0r, tv/td, rv (rw3 is row-
// independent!). Per-row: stage + a2p/rwDp prefetched a full compute phase
// ahead; ONE barrier per row; champion f4 hot loop; nt float4 stores.
// ---------------------------------------------------------------------------
__global__ __launch_bounds__(256) void k_main(const float* __restrict__ in,
                                              const float* __restrict__ w,
                                              const float* __restrict__ rw3,
                                              const float* __restrict__ a2p,
                                              const float* __restrict__ rwDp,
                                              const float* __restrict__ tb,
                                              const float* __restrict__ ttd,
                                              float* __restrict__ out) {
    __shared__ float inRow[2][NN * PADL];   // 20.5KB (double buffer)
    const int t = threadIdx.x;
    const int blk = blockIdx.x;          // matches k_rowsum block exactly
    const int rowBase = blk * 4;
    const int b = rowBase >> 7, i0 = rowBase & 127;
    const int fq = t & 7;                // f base = 4*fq
    const int jg = t >> 3;               // 0..31

    // ---- per-block hoisted loads ----
    float4 w0r[LL];
#pragma unroll
    for (int q = 0; q < LL; ++q)
        w0r[q] = *reinterpret_cast<const float4*>(&w[q * 6 * FF + 4 * fq]);
    const float4 tv = *reinterpret_cast<const float4*>(&tb[b * FF + 4 * fq]);
    const float4 td = *reinterpret_cast<const float4*>(&ttd[b * FF + 4 * fq]);
    const float* rw3b = rw3 + (size_t)b * NN * FF + 4 * fq;
    float4 rv[4];                        // shared by all 4 rows (same b)
#pragma unroll
    for (int p = 0; p < 4; ++p)
        rv[p] = *reinterpret_cast<const float4*>(&rw3b[(size_t)(jg + 32 * p) * FF]);

    const float4* src4 = reinterpret_cast<const float4*>(in) + (size_t)rowBase * 512;

    // ---- row 0: stage + av/dv ----
    float4 sa = src4[t], sb = src4[t + 256];
    float4 avc = *reinterpret_cast<const float4*>(&a2p[(size_t)rowBase * FF + 4 * fq]);
    float4 dvc = *reinterpret_cast<const float4*>(&rwDp[(size_t)rowBase * FF + 4 * fq]);
    avc.x += tv.x; avc.y += tv.y; avc.z += tv.z; avc.w += tv.w;
    dvc.x += td.x; dvc.y += td.y; dvc.z += td.z; dvc.w += td.w;
    {
        int j = t >> 2, c = t & 3;
        *reinterpret_cast<float4*>(&inRow[0][j * PADL + c * 4]) = sa;
        int idx = t + 256;
        j = idx >> 2; c = idx & 3;
        *reinterpret_cast<float4*>(&inRow[0][j * PADL + c * 4]) = sb;
    }
    __syncthreads();

#pragma unroll
    for (int r = 0; r < 4; ++r) {
        // prefetch next row (loads issue before this row's compute)
        float4 sna, snb, avn, dvn;
        if (r < 3) {
            sna = src4[(r + 1) * 512 + t];
            snb = src4[(r + 1) * 512 + t + 256];
            avn = *reinterpret_cast<const float4*>(&a2p[(size_t)(rowBase + r + 1) * FF + 4 * fq]);
            dvn = *reinterpret_cast<const float4*>(&rwDp[(size_t)(rowBase + r + 1) * FF + 4 * fq]);
        }

        const float* buf = inRow[r & 1];
        float* outr = out + (size_t)(rowBase + r) * NN * FF + 4 * fq;
        const int i = i0 + r;

#pragma unroll
        for (int p = 0; p < 4; ++p) {
            int j = jg + 32 * p;
            float4 acc;
            acc.x = avc.x + rv[p].x;
            acc.y = avc.y + rv[p].y;
            acc.z = avc.z + rv[p].z;
            acc.w = avc.w + rv[p].w;
            if (j == i) {
                acc.x += dvc.x; acc.y += dvc.y; acc.z += dvc.z; acc.w += dvc.w;
            }
            const float4* xr = reinterpret_cast<const float4*>(&buf[j * PADL]);
            float xv[LL];
            *reinterpret_cast<float4*>(&xv[0])  = xr[0];
            *reinterpret_cast<float4*>(&xv[4])  = xr[1];
            *reinterpret_cast<float4*>(&xv[8])  = xr[2];
            *reinterpret_cast<float4*>(&xv[12]) = xr[3];
#pragma unroll
            for (int q = 0; q < LL; ++q) {
                acc.x += xv[q] * w0r[q].x;
                acc.y += xv[q] * w0r[q].y;
                acc.z += xv[q] * w0r[q].z;
                acc.w += xv[q] * w0r[q].w;
            }
            nfloat4 o;
            o.x = fmaxf(acc.x, 0.f);
            o.y = fmaxf(acc.y, 0.f);
            o.z = fmaxf(acc.z, 0.f);
            o.w = fmaxf(acc.w, 0.f);
            __builtin_nontemporal_store(o, reinterpret_cast<nfloat4*>(&outr[(size_t)j * FF]));
        }

        if (r < 3) {
            // write next buffer (loads have had the whole compute phase to land)
            float* nbuf = inRow[(r + 1) & 1];
            int j = t >> 2, c = t & 3;
            *reinterpret_cast<float4*>(&nbuf[j * PADL + c * 4]) = sna;
            int idx = t + 256;
            j = idx >> 2; c = idx & 3;
            *reinterpret_cast<float4*>(&nbuf[j * PADL + c * 4]) = snb;
            avc.x = avn.x + tv.x; avc.y = avn.y + tv.y;
            avc.z = avn.z + tv.z; avc.w = avn.w + tv.w;
            dvc.x = dvn.x + td.x; dvc.y = dvn.y + td.y;
            dvc.z = dvn.z + td.z; dvc.w = dvn.w + td.w;
        }
        __syncthreads();
    }
}

extern "C" void kernel_launch(void* const* d_in, const int* in_sizes, int n_in,
                              void* d_out, int out_size, void* d_ws, size_t ws_size,
                              hipStream_t stream) {
    const float* in    = (const float*)d_in[0];   // [B,N,N,L] fp32
    const float* w     = (const float*)d_in[1];   // [L,6,F]
    const float* bias  = (const float*)d_in[2];   // [F]
    const float* dbias = (const float*)d_in[3];   // [F]
    float* out = (float*)d_out;                   // [B,N,N,F] fp32
    float* ws  = (float*)d_ws;

    float* tsp  = ws;                                  // 1024*16  = 16384 floats
    float* rw3  = tsp  + (size_t)1024 * LL;            // B*N*F    = 131072
    float* a2p  = rw3  + (size_t)BB * NN * FF;         // 131072
    float* rwDp = a2p  + (size_t)BB * NN * FF;         // 131072
    float* tb   = rwDp + (size_t)BB * NN * FF;         // B*F      = 1024
    float* ttd  = tb   + (size_t)BB * FF;              // 1024   (~1.65MB total)

    k_rowsum<<<BB * NN / 4, 256, 0, stream>>>(in, w, tsp, rw3, a2p, rwDp);
    k_tot   <<<BB,          256, 0, stream>>>(tsp, w, bias, dbias, tb, ttd);
    k_main  <<<BB * NN / 4, 256, 0, stream>>>(in, w, rw3, a2p, rwDp, tb, ttd, out);
}